// Round 1
// baseline (554.122 us; speedup 1.0000x reference)
//
#include <hip/hip_runtime.h>
#include <hip/hip_bf16.h>

#define B_SZ 4096
#define F_N 16
#define V_SZ 20000
#define E_SZ 64
#define HID 1024

// ---------------------------------------------------------------------------
// Gather: xw[b, f*64+e] = emb[f, idx[b,f], e]   (float4 per thread)
// ---------------------------------------------------------------------------
__global__ __launch_bounds__(256) void gather_kernel(
    const int* __restrict__ idx, const float* __restrict__ emb,
    float* __restrict__ xw) {
  int i = blockIdx.x * 256 + threadIdx.x;  // f4 index in [0, B*256)
  int b = i >> 8;
  int r = i & 255;   // f4 within the 1024-float row
  int f = r >> 4;    // field
  int e4 = r & 15;   // f4 within the 64-float embed row
  int id = idx[b * F_N + f];
  const float4 v =
      *(const float4*)(emb + ((size_t)f * V_SZ + id) * E_SZ + e4 * 4);
  *(float4*)(xw + (size_t)b * 1024 + r * 4) = v;
}

// ---------------------------------------------------------------------------
// C = relu(A @ W + bias);  A:[M,1024] W:[1024,1024] C:[M,1024]
// Tile 128x64, BK=32, 256 threads, 8x4 per thread, fp32 VALU.
// ---------------------------------------------------------------------------
#define TM 128
#define TN 64
#define TK 32

__global__ __launch_bounds__(256) void gemm_relu(
    const float* __restrict__ A, const float* __restrict__ W,
    const float* __restrict__ bias, float* __restrict__ C) {
  __shared__ float As[TK][TM];  // 16 KB, stored transposed
  __shared__ float Bs[TK][TN];  // 8 KB

  const int t = threadIdx.x;
  const int bm = blockIdx.y * TM;
  const int bn = blockIdx.x * TN;
  const int tx = t & 15;   // N dim, 4 cols each
  const int ty = t >> 4;   // M dim, 8 rows each

  float acc[8][4];
#pragma unroll
  for (int i = 0; i < 8; i++)
#pragma unroll
    for (int j = 0; j < 4; j++) acc[i][j] = 0.f;

  for (int k0 = 0; k0 < 1024; k0 += TK) {
    // A tile: 128 rows x 32 cols = 1024 float4, 4 per thread; store transposed
#pragma unroll
    for (int q = 0; q < 4; ++q) {
      int idx4 = t + q * 256;    // 0..1023
      int row = idx4 >> 3;       // 8 f4 per 32-float row
      int c4 = idx4 & 7;
      float4 v = *(const float4*)(A + (size_t)(bm + row) * 1024 + k0 + c4 * 4);
      As[c4 * 4 + 0][row] = v.x;
      As[c4 * 4 + 1][row] = v.y;
      As[c4 * 4 + 2][row] = v.z;
      As[c4 * 4 + 3][row] = v.w;
    }
    // B tile: 32 rows x 64 cols = 512 float4, 2 per thread
#pragma unroll
    for (int q = 0; q < 2; ++q) {
      int idx4 = t + q * 256;  // 0..511
      int row = idx4 >> 4;     // 16 f4 per 64-float row
      int c4 = idx4 & 15;
      *(float4*)&Bs[row][c4 * 4] =
          *(const float4*)(W + (size_t)(k0 + row) * 1024 + bn + c4 * 4);
    }
    __syncthreads();

#pragma unroll
    for (int kk = 0; kk < TK; ++kk) {
      float a[8], b[4];
#pragma unroll
      for (int i = 0; i < 8; i++) a[i] = As[kk][ty * 8 + i];
#pragma unroll
      for (int j = 0; j < 4; j++) b[j] = Bs[kk][tx * 4 + j];
#pragma unroll
      for (int i = 0; i < 8; i++)
#pragma unroll
        for (int j = 0; j < 4; j++) acc[i][j] = fmaf(a[i], b[j], acc[i][j]);
    }
    __syncthreads();
  }

#pragma unroll
  for (int i = 0; i < 8; i++) {
    int row = bm + ty * 8 + i;
    float4 v;
    float* vp = &v.x;
#pragma unroll
    for (int j = 0; j < 4; j++) {
      float x = acc[i][j] + bias[bn + tx * 4 + j];
      vp[j] = x > 0.f ? x : 0.f;
    }
    *(float4*)(C + (size_t)row * 1024 + bn + tx * 4) = v;
  }
}

// ---------------------------------------------------------------------------
// Attention-over-layers + final dot.
// Hm[b,j] = cat[3b+j] with cat = [l0; l1; l2] row-stacked  (faithful to the
// reference's concat(axis=0).reshape(B,NL,HID)).
// One wave per batch row.
// ---------------------------------------------------------------------------
__global__ __launch_bounds__(256) void attn_final(
    const float* __restrict__ cat, const float* __restrict__ lf,
    const float* __restrict__ wf, const float* __restrict__ bfin,
    float* __restrict__ out) {
  const int wave = threadIdx.x >> 6;
  const int lane = threadIdx.x & 63;
  const int b = blockIdx.x * 4 + wave;

  const float* h0 = cat + (size_t)(3 * b + 0) * 1024;
  const float* h1 = cat + (size_t)(3 * b + 1) * 1024;
  const float* h2 = cat + (size_t)(3 * b + 2) * 1024;
  const float* lfr = lf + (size_t)b * 1024;

  float s01 = 0.f, s02 = 0.f, s12 = 0.f;
  float d0 = 0.f, d1 = 0.f, d2 = 0.f, dl = 0.f;

#pragma unroll
  for (int q = 0; q < 4; ++q) {
    int f4 = lane + q * 64;  // [0,256)
    float4 a0 = *(const float4*)(h0 + f4 * 4);
    float4 a1 = *(const float4*)(h1 + f4 * 4);
    float4 a2 = *(const float4*)(h2 + f4 * 4);
    float4 al = *(const float4*)(lfr + f4 * 4);
    float4 u0 = *(const float4*)(wf + f4 * 4);          // wf[0:1024]
    float4 u1 = *(const float4*)(wf + 1024 + f4 * 4);   // wf[1024:2048]
    const float* p0 = &a0.x; const float* p1 = &a1.x; const float* p2 = &a2.x;
    const float* pl = &al.x; const float* q0 = &u0.x; const float* q1 = &u1.x;
#pragma unroll
    for (int j = 0; j < 4; ++j) {
      s01 = fmaf(p0[j], p1[j], s01);
      s02 = fmaf(p0[j], p2[j], s02);
      s12 = fmaf(p1[j], p2[j], s12);
      d0 = fmaf(p0[j], q1[j], d0);
      d1 = fmaf(p1[j], q1[j], d1);
      d2 = fmaf(p2[j], q1[j], d2);
      dl = fmaf(pl[j], q0[j], dl);
    }
  }

  // wave-wide xor-tree reduction of the 7 partials
#pragma unroll
  for (int m = 1; m < 64; m <<= 1) {
    s01 += __shfl_xor(s01, m);
    s02 += __shfl_xor(s02, m);
    s12 += __shfl_xor(s12, m);
    d0 += __shfl_xor(d0, m);
    d1 += __shfl_xor(d1, m);
    d2 += __shfl_xor(d2, m);
    dl += __shfl_xor(dl, m);
  }

  if (lane == 0) {
    // S rows (diag masked to 0, INCLUDED in softmax):
    // row0 = [0, s01, s02]; row1 = [s01, 0, s12]; row2 = [s02, s12, 0]
    float c0 = 0.f, c1 = 0.f, c2 = 0.f;
    {
      float m = fmaxf(0.f, fmaxf(s01, s02));
      float e0 = expf(0.f - m), e1 = expf(s01 - m), e2 = expf(s02 - m);
      float inv = 1.f / (e0 + e1 + e2);
      c0 += e0 * inv; c1 += e1 * inv; c2 += e2 * inv;
    }
    {
      float m = fmaxf(s01, fmaxf(0.f, s12));
      float e0 = expf(s01 - m), e1 = expf(0.f - m), e2 = expf(s12 - m);
      float inv = 1.f / (e0 + e1 + e2);
      c0 += e0 * inv; c1 += e1 * inv; c2 += e2 * inv;
    }
    {
      float m = fmaxf(s02, fmaxf(s12, 0.f));
      float e0 = expf(s02 - m), e1 = expf(s12 - m), e2 = expf(0.f - m);
      float inv = 1.f / (e0 + e1 + e2);
      c0 += e0 * inv; c1 += e1 * inv; c2 += e2 * inv;
    }
    out[b] = dl + c0 * d0 + c1 * d1 + c2 * d2 + bfin[0];
  }
}

// ---------------------------------------------------------------------------
extern "C" void kernel_launch(void* const* d_in, const int* in_sizes, int n_in,
                              void* d_out, int out_size, void* d_ws,
                              size_t ws_size, hipStream_t stream) {
  const int* idx = (const int*)d_in[0];
  const float* emb = (const float*)d_in[1];
  const float* w0 = (const float*)d_in[2];
  const float* b0 = (const float*)d_in[3];
  const float* w1 = (const float*)d_in[4];
  const float* b1 = (const float*)d_in[5];
  const float* w2 = (const float*)d_in[6];
  const float* b2 = (const float*)d_in[7];
  const float* w3 = (const float*)d_in[8];
  const float* b3 = (const float*)d_in[9];
  const float* wf = (const float*)d_in[10];
  const float* bfin = (const float*)d_in[11];
  float* out = (float*)d_out;

  const size_t RB = (size_t)B_SZ * HID;  // 4M floats
  float* xw = (float*)d_ws;              // [B,1024]
  float* cat = xw + RB;                  // [3B,1024]  (l0;l1;l2)
  float* lf = cat + 3 * RB;              // [B,1024]

  gather_kernel<<<B_SZ, 256, 0, stream>>>(idx, emb, xw);

  dim3 g(HID / TN, B_SZ / TM);  // 16 x 32
  gemm_relu<<<g, 256, 0, stream>>>(xw, w0, b0, cat);               // l0
  gemm_relu<<<g, 256, 0, stream>>>(cat, w1, b1, cat + RB);         // l1
  gemm_relu<<<g, 256, 0, stream>>>(cat + RB, w2, b2, cat + 2 * RB);// l2
  gemm_relu<<<g, 256, 0, stream>>>(cat + 2 * RB, w3, b3, lf);      // l_final

  attn_final<<<B_SZ / 4, 256, 0, stream>>>(cat, lf, wf, bfin, out);
}

// Round 2
// 146.740 us; speedup vs baseline: 3.7762x; 3.7762x over previous
//
#include <hip/hip_runtime.h>
#include <hip/hip_bf16.h>
#include <stdint.h>

#define B_SZ 4096
#define F_N 16
#define V_SZ 20000
#define E_SZ 64
#define HID 1024

typedef __attribute__((ext_vector_type(8))) _Float16 f16x8;
typedef __attribute__((ext_vector_type(4))) _Float16 f16x4;
typedef __attribute__((ext_vector_type(4))) float f32x4;

__device__ __forceinline__ void gload16(const void* g, void* l) {
  __builtin_amdgcn_global_load_lds(
      (const __attribute__((address_space(1))) void*)g,
      (__attribute__((address_space(3))) void*)l, 16, 0, 0);
}

// ---------------------------------------------------------------------------
// Weight convert + transpose: wt[z][n][k] = (f16) w_z[k][n]
// ---------------------------------------------------------------------------
__global__ __launch_bounds__(256) void convert_w(
    const float* __restrict__ w0, const float* __restrict__ w1,
    const float* __restrict__ w2, const float* __restrict__ w3,
    _Float16* __restrict__ wt) {
  const float* w = (blockIdx.z == 0) ? w0
                 : (blockIdx.z == 1) ? w1
                 : (blockIdx.z == 2) ? w2 : w3;
  _Float16* out = wt + (size_t)blockIdx.z * HID * HID;
  __shared__ float tile[32][33];
  const int tx = threadIdx.x & 31, ty = threadIdx.x >> 5;
  const int k0 = blockIdx.x * 32, n0 = blockIdx.y * 32;
#pragma unroll
  for (int q = 0; q < 4; ++q) {
    int r = ty + q * 8;
    tile[r][tx] = w[(size_t)(k0 + r) * HID + n0 + tx];
  }
  __syncthreads();
#pragma unroll
  for (int q = 0; q < 4; ++q) {
    int r = ty + q * 8;
    out[(size_t)(n0 + r) * HID + k0 + tx] = (_Float16)tile[tx][r];
  }
}

// ---------------------------------------------------------------------------
// Gather straight to f16: xw[b, f*64+e] = emb[f, idx[b,f], e]
// ---------------------------------------------------------------------------
__global__ __launch_bounds__(256) void gather_f16(
    const int* __restrict__ idx, const float* __restrict__ emb,
    _Float16* __restrict__ xw) {
  int i = blockIdx.x * 256 + threadIdx.x;  // f4 index in [0, B*256)
  int b = i >> 8;
  int r = i & 255;
  int f = r >> 4;
  int e4 = r & 15;
  int id = idx[b * F_N + f];
  float4 v = *(const float4*)(emb + ((size_t)f * V_SZ + id) * E_SZ + e4 * 4);
  f16x4 h = {(_Float16)v.x, (_Float16)v.y, (_Float16)v.z, (_Float16)v.w};
  *(f16x4*)(xw + (size_t)b * HID + r * 4) = h;
}

// ---------------------------------------------------------------------------
// C = relu(A @ Wt^T + bias), MFMA f16, 128x128 tile, BK=32, 4 waves (64x64),
// 2-phase double-buffered LDS staging via global_load_lds width=16.
// A: [M,1024] f16 row-major; Wt: [1024 n][1024 k] f16 (pre-transposed).
// Writes Cf (f32) always, Ch (f16) if non-null.
// ---------------------------------------------------------------------------
__global__ __launch_bounds__(256) void gemm_mfma(
    const _Float16* __restrict__ A, const _Float16* __restrict__ Wt,
    const float* __restrict__ bias, float* __restrict__ Cf,
    _Float16* __restrict__ Ch) {
  __shared__ _Float16 As[2][128 * 32];
  __shared__ _Float16 Bs[2][128 * 32];

  const int t = threadIdx.x;
  const int bm = blockIdx.y * 128, bn = blockIdx.x * 128;
  const int w = t >> 6, lane = t & 63;
  const int wr = w >> 1, wc = w & 1;
  const int lr = lane & 15, lg = lane >> 4;

  // staging addresses: thread t loads rows (t>>2) and (t>>2)+64, k-chunk (t&3)*8
  const int srow = t >> 2, skk = (t & 3) * 8;
  const _Float16* ga0 = A + (size_t)(bm + srow) * HID + skk;
  const _Float16* ga1 = A + (size_t)(bm + srow + 64) * HID + skk;
  const _Float16* gb0 = Wt + (size_t)(bn + srow) * HID + skk;
  const _Float16* gb1 = Wt + (size_t)(bn + srow + 64) * HID + skk;
  const int ldst = srow * 32 + skk;  // == t*8 halves == t*16 bytes

  f32x4 acc[4][4] = {};

  // prologue: stage k0=0 into buf 0
  gload16(ga0, &As[0][ldst]);
  gload16(ga1, &As[0][ldst + 64 * 32]);
  gload16(gb0, &Bs[0][ldst]);
  gload16(gb1, &Bs[0][ldst + 64 * 32]);
  __syncthreads();

  int cur = 0;
  for (int k0 = 0; k0 < HID; k0 += 32) {
    if (k0 + 32 < HID) {
      int nxt = cur ^ 1;
      int ko = k0 + 32;
      gload16(ga0 + ko, &As[nxt][ldst]);
      gload16(ga1 + ko, &As[nxt][ldst + 64 * 32]);
      gload16(gb0 + ko, &Bs[nxt][ldst]);
      gload16(gb1 + ko, &Bs[nxt][ldst + 64 * 32]);
    }
    f16x8 a[4], b[4];
#pragma unroll
    for (int mi = 0; mi < 4; mi++)
      a[mi] = *(const f16x8*)&As[cur][(wr * 64 + mi * 16 + lr) * 32 + lg * 8];
#pragma unroll
    for (int ni = 0; ni < 4; ni++)
      b[ni] = *(const f16x8*)&Bs[cur][(wc * 64 + ni * 16 + lr) * 32 + lg * 8];
#pragma unroll
    for (int mi = 0; mi < 4; mi++)
#pragma unroll
      for (int ni = 0; ni < 4; ni++)
        acc[mi][ni] = __builtin_amdgcn_mfma_f32_16x16x32_f16(
            a[mi], b[ni], acc[mi][ni], 0, 0, 0);
    __syncthreads();  // drains vmcnt (stage done) + lgkm; guards buffer reuse
    cur ^= 1;
  }

  // epilogue: D col = lane&15, row = (lane>>4)*4 + reg
#pragma unroll
  for (int ni = 0; ni < 4; ni++) {
    int col = bn + wc * 64 + ni * 16 + lr;
    float bv = bias[col];
#pragma unroll
    for (int mi = 0; mi < 4; mi++) {
      int rbase = bm + wr * 64 + mi * 16 + lg * 4;
#pragma unroll
      for (int j = 0; j < 4; j++) {
        float x = acc[mi][ni][j] + bv;
        x = x > 0.f ? x : 0.f;
        Cf[(size_t)(rbase + j) * HID + col] = x;
        if (Ch) Ch[(size_t)(rbase + j) * HID + col] = (_Float16)x;
      }
    }
  }
}

// ---------------------------------------------------------------------------
// Attention-over-layers + final dot (fp32, unchanged from passing round).
// Hm[b,j] = cat[3b+j] with cat = [l0; l1; l2] row-stacked.
// ---------------------------------------------------------------------------
__global__ __launch_bounds__(256) void attn_final(
    const float* __restrict__ cat, const float* __restrict__ lf,
    const float* __restrict__ wf, const float* __restrict__ bfin,
    float* __restrict__ out) {
  const int wave = threadIdx.x >> 6;
  const int lane = threadIdx.x & 63;
  const int b = blockIdx.x * 4 + wave;

  const float* h0 = cat + (size_t)(3 * b + 0) * 1024;
  const float* h1 = cat + (size_t)(3 * b + 1) * 1024;
  const float* h2 = cat + (size_t)(3 * b + 2) * 1024;
  const float* lfr = lf + (size_t)b * 1024;

  float s01 = 0.f, s02 = 0.f, s12 = 0.f;
  float d0 = 0.f, d1 = 0.f, d2 = 0.f, dl = 0.f;

#pragma unroll
  for (int q = 0; q < 4; ++q) {
    int f4 = lane + q * 64;
    float4 a0 = *(const float4*)(h0 + f4 * 4);
    float4 a1 = *(const float4*)(h1 + f4 * 4);
    float4 a2 = *(const float4*)(h2 + f4 * 4);
    float4 al = *(const float4*)(lfr + f4 * 4);
    float4 u0 = *(const float4*)(wf + f4 * 4);
    float4 u1 = *(const float4*)(wf + 1024 + f4 * 4);
    const float* p0 = &a0.x; const float* p1 = &a1.x; const float* p2 = &a2.x;
    const float* pl = &al.x; const float* q0 = &u0.x; const float* q1 = &u1.x;
#pragma unroll
    for (int j = 0; j < 4; ++j) {
      s01 = fmaf(p0[j], p1[j], s01);
      s02 = fmaf(p0[j], p2[j], s02);
      s12 = fmaf(p1[j], p2[j], s12);
      d0 = fmaf(p0[j], q1[j], d0);
      d1 = fmaf(p1[j], q1[j], d1);
      d2 = fmaf(p2[j], q1[j], d2);
      dl = fmaf(pl[j], q0[j], dl);
    }
  }

#pragma unroll
  for (int m = 1; m < 64; m <<= 1) {
    s01 += __shfl_xor(s01, m);
    s02 += __shfl_xor(s02, m);
    s12 += __shfl_xor(s12, m);
    d0 += __shfl_xor(d0, m);
    d1 += __shfl_xor(d1, m);
    d2 += __shfl_xor(d2, m);
    dl += __shfl_xor(dl, m);
  }

  if (lane == 0) {
    float c0 = 0.f, c1 = 0.f, c2 = 0.f;
    {
      float m = fmaxf(0.f, fmaxf(s01, s02));
      float e0 = expf(0.f - m), e1 = expf(s01 - m), e2 = expf(s02 - m);
      float inv = 1.f / (e0 + e1 + e2);
      c0 += e0 * inv; c1 += e1 * inv; c2 += e2 * inv;
    }
    {
      float m = fmaxf(s01, fmaxf(0.f, s12));
      float e0 = expf(s01 - m), e1 = expf(0.f - m), e2 = expf(s12 - m);
      float inv = 1.f / (e0 + e1 + e2);
      c0 += e0 * inv; c1 += e1 * inv; c2 += e2 * inv;
    }
    {
      float m = fmaxf(s02, fmaxf(s12, 0.f));
      float e0 = expf(s02 - m), e1 = expf(s12 - m), e2 = expf(0.f - m);
      float inv = 1.f / (e0 + e1 + e2);
      c0 += e0 * inv; c1 += e1 * inv; c2 += e2 * inv;
    }
    out[b] = dl + c0 * d0 + c1 * d1 + c2 * d2 + bfin[0];
  }
}

// ---------------------------------------------------------------------------
extern "C" void kernel_launch(void* const* d_in, const int* in_sizes, int n_in,
                              void* d_out, int out_size, void* d_ws,
                              size_t ws_size, hipStream_t stream) {
  const int* idx = (const int*)d_in[0];
  const float* emb = (const float*)d_in[1];
  const float* w0 = (const float*)d_in[2];
  const float* b0 = (const float*)d_in[3];
  const float* w1 = (const float*)d_in[4];
  const float* b1 = (const float*)d_in[5];
  const float* w2 = (const float*)d_in[6];
  const float* b2 = (const float*)d_in[7];
  const float* w3 = (const float*)d_in[8];
  const float* b3 = (const float*)d_in[9];
  const float* wf = (const float*)d_in[10];
  const float* bfin = (const float*)d_in[11];
  float* out = (float*)d_out;

  const size_t RB = (size_t)B_SZ * HID;  // 4M elements

  float* cat = (float*)d_ws;             // [3B,1024] f32 (l0;l1;l2) 48 MB
  float* lf = cat + 3 * RB;              // [B,1024] f32            16 MB
  _Float16* xw16 = (_Float16*)(lf + RB); // [B,1024] f16             8 MB
  _Float16* cat16 = xw16 + RB;           // [3][B,1024] f16         24 MB
  _Float16* wt = cat16 + 3 * RB;         // [4][1024][1024] f16      8 MB

  convert_w<<<dim3(32, 32, 4), 256, 0, stream>>>(w0, w1, w2, w3, wt);
  gather_f16<<<B_SZ, 256, 0, stream>>>(idx, emb, xw16);

  dim3 g(HID / 128, B_SZ / 128);  // 8 x 32 = 256 blocks
  const size_t WSZ = (size_t)HID * HID;
  gemm_mfma<<<g, 256, 0, stream>>>(xw16, wt + 0 * WSZ, b0, cat, cat16);
  gemm_mfma<<<g, 256, 0, stream>>>(cat16, wt + 1 * WSZ, b1, cat + RB,
                                   cat16 + RB);
  gemm_mfma<<<g, 256, 0, stream>>>(cat16 + RB, wt + 2 * WSZ, b2, cat + 2 * RB,
                                   cat16 + 2 * RB);
  gemm_mfma<<<g, 256, 0, stream>>>(cat16 + 2 * RB, wt + 3 * WSZ, b3, lf,
                                   (_Float16*)nullptr);

  attn_final<<<B_SZ / 4, 256, 0, stream>>>(cat, lf, wf, bfin, out);
}

// Round 3
// 113.882 us; speedup vs baseline: 4.8658x; 1.2885x over previous
//
#include <hip/hip_runtime.h>
#include <hip/hip_bf16.h>
#include <stdint.h>

#define B_SZ 4096
#define F_N 16
#define V_SZ 20000
#define E_SZ 64
#define HID 1024

typedef __attribute__((ext_vector_type(8))) _Float16 f16x8;
typedef __attribute__((ext_vector_type(4))) _Float16 f16x4;
typedef __attribute__((ext_vector_type(4))) float f32x4;

__device__ __forceinline__ void gload16(const void* g, void* l) {
  __builtin_amdgcn_global_load_lds(
      (const __attribute__((address_space(1))) void*)g,
      (__attribute__((address_space(3))) void*)l, 16, 0, 0);
}

// ---------------------------------------------------------------------------
// prep: blocks [0,4096) convert+transpose weights (wt[z][n][k] = f16 w_z[k][n]);
//       blocks [4096,8192) gather embeddings straight to f16.
// ---------------------------------------------------------------------------
__global__ __launch_bounds__(256) void prep(
    const int* __restrict__ idx, const float* __restrict__ emb,
    const float* __restrict__ w0, const float* __restrict__ w1,
    const float* __restrict__ w2, const float* __restrict__ w3,
    _Float16* __restrict__ wt, _Float16* __restrict__ xw) {
  const int cb = blockIdx.x;
  if (cb < 4096) {
    const int z = cb >> 10, rem = cb & 1023;
    const float* w = (z == 0) ? w0 : (z == 1) ? w1 : (z == 2) ? w2 : w3;
    _Float16* outp = wt + (size_t)z * HID * HID;
    __shared__ float tile[32][33];
    const int tx = threadIdx.x & 31, ty = threadIdx.x >> 5;
    const int k0 = (rem >> 5) * 32, n0 = (rem & 31) * 32;
#pragma unroll
    for (int q = 0; q < 4; ++q) {
      int r = ty + q * 8;
      tile[r][tx] = w[(size_t)(k0 + r) * HID + n0 + tx];
    }
    __syncthreads();
#pragma unroll
    for (int q = 0; q < 4; ++q) {
      int r = ty + q * 8;
      outp[(size_t)(n0 + r) * HID + k0 + tx] = (_Float16)tile[tx][r];
    }
  } else {
    int i = (cb - 4096) * 256 + threadIdx.x;  // f4 index in [0, B*256)
    int b = i >> 8;
    int r = i & 255;
    int f = r >> 4;
    int e4 = r & 15;
    int id = idx[b * F_N + f];
    float4 v = *(const float4*)(emb + ((size_t)f * V_SZ + id) * E_SZ + e4 * 4);
    f16x4 h = {(_Float16)v.x, (_Float16)v.y, (_Float16)v.z, (_Float16)v.w};
    *(f16x4*)(xw + (size_t)b * HID + r * 4) = h;
  }
}

// ---------------------------------------------------------------------------
// C = relu(A @ Wt^T + bias) -> f16.  MFMA 16x16x32_f16, 128x128 tile, BK=32,
// 4 waves (64x64 each). Depth-2 prefetch: 3 LDS buffers, raw s_barrier +
// counted vmcnt (T4). LDS bank-conflict fix (T2) via pre-swizzled global
// source chunk + swizzled read, linear LDS dest:
//   LDS[r][c] holds global chunk c ^ s(r),  s(r) = (r ^ (r>>2)) & 3
// so lanes lr=0..15 (row stride 64B) spread 2-way across banks (free).
// ---------------------------------------------------------------------------
__global__ __launch_bounds__(256) void gemm_mfma(
    const _Float16* __restrict__ A, const _Float16* __restrict__ Wt,
    const float* __restrict__ bias, _Float16* __restrict__ C) {
  __shared__ _Float16 As[3][128 * 32];
  __shared__ _Float16 Bs[3][128 * 32];

  const int t = threadIdx.x;
  const int bm = blockIdx.y * 128, bn = blockIdx.x * 128;
  const int w = t >> 6, lane = t & 63;
  const int wr = w >> 1, wc = w & 1;
  const int lr = lane & 15, lg = lane >> 4;

  // staging: thread t covers rows srow, srow+64; 16B chunk cdst of the 64B row
  const int srow = t >> 2;
  const int cdst = t & 3;
  const int csrc = cdst ^ ((srow ^ (srow >> 2)) & 3);  // s(srow)==s(srow+64)
  const _Float16* ga0 = A + (size_t)(bm + srow) * HID + csrc * 8;
  const _Float16* ga1 = A + (size_t)(bm + srow + 64) * HID + csrc * 8;
  const _Float16* gb0 = Wt + (size_t)(bn + srow) * HID + csrc * 8;
  const _Float16* gb1 = Wt + (size_t)(bn + srow + 64) * HID + csrc * 8;
  const int ld0 = srow * 32 + cdst * 8;  // halves (linear dest)
  const int ld1 = ld0 + 64 * 32;

  // read offsets (halves), constant across K-steps
  int aoff[4], boff[4];
#pragma unroll
  for (int mi = 0; mi < 4; mi++) {
    int ra = wr * 64 + mi * 16 + lr;
    aoff[mi] = ra * 32 + ((lg ^ ((ra ^ (ra >> 2)) & 3)) * 8);
    int rb = wc * 64 + mi * 16 + lr;
    boff[mi] = rb * 32 + ((lg ^ ((rb ^ (rb >> 2)) & 3)) * 8);
  }

  f32x4 acc[4][4] = {};

#define STAGE(buf, ko)                  \
  gload16(ga0 + (ko), &As[buf][ld0]);   \
  gload16(ga1 + (ko), &As[buf][ld1]);   \
  gload16(gb0 + (ko), &Bs[buf][ld0]);   \
  gload16(gb1 + (ko), &Bs[buf][ld1]);

  STAGE(0, 0)      // tile 0
  STAGE(1, 32)     // tile 1

  int cur = 0, nb = 2;
  for (int tI = 0; tI < 32; ++tI) {
    if (tI < 30) {
      STAGE(nb, (tI + 2) * 32)  // tile tI+2, 4 loads/thread
    }
    // wait for tile tI (issued 2 iters ago); keep newer tiles in flight
    if (tI < 30)
      asm volatile("s_waitcnt vmcnt(8)" ::: "memory");
    else if (tI == 30)
      asm volatile("s_waitcnt vmcnt(4)" ::: "memory");
    else
      asm volatile("s_waitcnt vmcnt(0)" ::: "memory");
    asm volatile("s_barrier" ::: "memory");  // all waves' tile-tI loads landed

    f16x8 a[4], b[4];
#pragma unroll
    for (int mi = 0; mi < 4; mi++) a[mi] = *(const f16x8*)&As[cur][aoff[mi]];
#pragma unroll
    for (int ni = 0; ni < 4; ni++) b[ni] = *(const f16x8*)&Bs[cur][boff[ni]];
#pragma unroll
    for (int mi = 0; mi < 4; mi++)
#pragma unroll
      for (int ni = 0; ni < 4; ni++)
        acc[mi][ni] = __builtin_amdgcn_mfma_f32_16x16x32_f16(
            a[mi], b[ni], acc[mi][ni], 0, 0, 0);

    // all lanes' ds_reads retired (lgkm waits precede dependent MFMAs);
    // gate next iteration's overwrite of buf (tI+3)%3 == cur
    asm volatile("s_barrier" ::: "memory");
    cur = (cur == 2) ? 0 : cur + 1;
    nb = (nb == 2) ? 0 : nb + 1;
  }
#undef STAGE

  // epilogue: D col = lane&15, row = (lane>>4)*4 + j
#pragma unroll
  for (int ni = 0; ni < 4; ni++) {
    int col = bn + wc * 64 + ni * 16 + lr;
    float bv = bias[col];
#pragma unroll
    for (int mi = 0; mi < 4; mi++) {
      int rbase = bm + wr * 64 + mi * 16 + lg * 4;
#pragma unroll
      for (int j = 0; j < 4; j++) {
        float x = acc[mi][ni][j] + bv;
        x = x > 0.f ? x : 0.f;
        C[(size_t)(rbase + j) * HID + col] = (_Float16)x;
      }
    }
  }
}

// ---------------------------------------------------------------------------
// Attention-over-layers + final dot; reads f16 activations, fp32 math.
// Hm[b,j] = cat[3b+j] with cat = [l0; l1; l2] row-stacked.
// ---------------------------------------------------------------------------
__global__ __launch_bounds__(256) void attn_final(
    const _Float16* __restrict__ cat, const _Float16* __restrict__ lf,
    const float* __restrict__ wf, const float* __restrict__ bfin,
    float* __restrict__ out) {
  const int wave = threadIdx.x >> 6;
  const int lane = threadIdx.x & 63;
  const int b = blockIdx.x * 4 + wave;

  const _Float16* h0 = cat + (size_t)(3 * b + 0) * 1024;
  const _Float16* h1 = cat + (size_t)(3 * b + 1) * 1024;
  const _Float16* h2 = cat + (size_t)(3 * b + 2) * 1024;
  const _Float16* lfr = lf + (size_t)b * 1024;

  float s01 = 0.f, s02 = 0.f, s12 = 0.f;
  float d0 = 0.f, d1 = 0.f, d2 = 0.f, dl = 0.f;

#pragma unroll
  for (int q = 0; q < 2; ++q) {
    int e8 = (lane + q * 64) * 8;  // 8 elements per lane per pass
    f16x8 a0 = *(const f16x8*)(h0 + e8);
    f16x8 a1 = *(const f16x8*)(h1 + e8);
    f16x8 a2 = *(const f16x8*)(h2 + e8);
    f16x8 al = *(const f16x8*)(lfr + e8);
    float4 u0a = *(const float4*)(wf + e8);
    float4 u0b = *(const float4*)(wf + e8 + 4);
    float4 u1a = *(const float4*)(wf + 1024 + e8);
    float4 u1b = *(const float4*)(wf + 1024 + e8 + 4);
    const float* q0 = &u0a.x;  // u0a,u0b contiguous in registers? use arrays
    float wf0[8] = {u0a.x, u0a.y, u0a.z, u0a.w, u0b.x, u0b.y, u0b.z, u0b.w};
    float wf1[8] = {u1a.x, u1a.y, u1a.z, u1a.w, u1b.x, u1b.y, u1b.z, u1b.w};
    (void)q0;
#pragma unroll
    for (int j = 0; j < 8; ++j) {
      float p0 = (float)a0[j], p1 = (float)a1[j], p2 = (float)a2[j];
      float pl = (float)al[j];
      s01 = fmaf(p0, p1, s01);
      s02 = fmaf(p0, p2, s02);
      s12 = fmaf(p1, p2, s12);
      d0 = fmaf(p0, wf1[j], d0);
      d1 = fmaf(p1, wf1[j], d1);
      d2 = fmaf(p2, wf1[j], d2);
      dl = fmaf(pl, wf0[j], dl);
    }
  }

#pragma unroll
  for (int m = 1; m < 64; m <<= 1) {
    s01 += __shfl_xor(s01, m);
    s02 += __shfl_xor(s02, m);
    s12 += __shfl_xor(s12, m);
    d0 += __shfl_xor(d0, m);
    d1 += __shfl_xor(d1, m);
    d2 += __shfl_xor(d2, m);
    dl += __shfl_xor(dl, m);
  }

  if (lane == 0) {
    float c0 = 0.f, c1 = 0.f, c2 = 0.f;
    {
      float m = fmaxf(0.f, fmaxf(s01, s02));
      float e0 = expf(0.f - m), e1 = expf(s01 - m), e2 = expf(s02 - m);
      float inv = 1.f / (e0 + e1 + e2);
      c0 += e0 * inv; c1 += e1 * inv; c2 += e2 * inv;
    }
    {
      float m = fmaxf(s01, fmaxf(0.f, s12));
      float e0 = expf(s01 - m), e1 = expf(0.f - m), e2 = expf(s12 - m);
      float inv = 1.f / (e0 + e1 + e2);
      c0 += e0 * inv; c1 += e1 * inv; c2 += e2 * inv;
    }
    {
      float m = fmaxf(s02, fmaxf(s12, 0.f));
      float e0 = expf(s02 - m), e1 = expf(s12 - m), e2 = expf(0.f - m);
      float inv = 1.f / (e0 + e1 + e2);
      c0 += e0 * inv; c1 += e1 * inv; c2 += e2 * inv;
    }
    out[b] = dl + c0 * d0 + c1 * d1 + c2 * d2 + bfin[0];
  }
}

// ---------------------------------------------------------------------------
extern "C" void kernel_launch(void* const* d_in, const int* in_sizes, int n_in,
                              void* d_out, int out_size, void* d_ws,
                              size_t ws_size, hipStream_t stream) {
  const int* idx = (const int*)d_in[0];
  const float* emb = (const float*)d_in[1];
  const float* w0 = (const float*)d_in[2];
  const float* b0 = (const float*)d_in[3];
  const float* w1 = (const float*)d_in[4];
  const float* b1 = (const float*)d_in[5];
  const float* w2 = (const float*)d_in[6];
  const float* b2 = (const float*)d_in[7];
  const float* w3 = (const float*)d_in[8];
  const float* b3 = (const float*)d_in[9];
  const float* wf = (const float*)d_in[10];
  const float* bfin = (const float*)d_in[11];
  float* out = (float*)d_out;

  const size_t RB = (size_t)B_SZ * HID;   // 4M elements
  const size_t WSZ = (size_t)HID * HID;   // 1M elements

  _Float16* wt = (_Float16*)d_ws;        // [4][1024][1024]  8 MB
  _Float16* xw16 = wt + 4 * WSZ;         // [B,1024]         8 MB
  _Float16* cat16 = xw16 + RB;           // [3B,1024]       24 MB
  _Float16* lf16 = cat16 + 3 * RB;       // [B,1024]         8 MB

  prep<<<8192, 256, 0, stream>>>(idx, emb, w0, w1, w2, w3, wt, xw16);

  dim3 g(HID / 128, B_SZ / 128);  // 8 x 32 = 256 blocks
  gemm_mfma<<<g, 256, 0, stream>>>(xw16, wt + 0 * WSZ, b0, cat16);
  gemm_mfma<<<g, 256, 0, stream>>>(cat16, wt + 1 * WSZ, b1, cat16 + RB);
  gemm_mfma<<<g, 256, 0, stream>>>(cat16 + RB, wt + 2 * WSZ, b2,
                                   cat16 + 2 * RB);
  gemm_mfma<<<g, 256, 0, stream>>>(cat16 + 2 * RB, wt + 3 * WSZ, b3, lf16);

  attn_final<<<B_SZ / 4, 256, 0, stream>>>(cat16, lf16, wf, bfin, out);
}

// Round 4
// 80.902 us; speedup vs baseline: 6.8493x; 1.4077x over previous
//
#include <hip/hip_runtime.h>
#include <hip/hip_bf16.h>
#include <stdint.h>

#define B_SZ 4096
#define F_N 16
#define V_SZ 20000
#define E_SZ 64
#define HID 1024

typedef __attribute__((ext_vector_type(8))) _Float16 f16x8;
typedef __attribute__((ext_vector_type(4))) _Float16 f16x4;
typedef __attribute__((ext_vector_type(4))) float f32x4;

__device__ __forceinline__ void gload16(const void* g, void* l) {
  __builtin_amdgcn_global_load_lds(
      (const __attribute__((address_space(1))) void*)g,
      (__attribute__((address_space(3))) void*)l, 16, 0, 0);
}

// s3(r): spreads a 128B-stride row-major LDS tile across the 8 16B bank
// groups. Note s3(r+64) == s3(r) (bit3 of r>>3 is dropped by &7).
__device__ __forceinline__ int s3(int r) { return (r ^ (r >> 3)) & 7; }

// ---------------------------------------------------------------------------
// prep: blocks [0,4096) convert+transpose weights (wt[z][n][k] = f16 w_z[k][n]);
//       blocks [4096,8192) gather embeddings straight to f16.
// ---------------------------------------------------------------------------
__global__ __launch_bounds__(256) void prep(
    const int* __restrict__ idx, const float* __restrict__ emb,
    const float* __restrict__ w0, const float* __restrict__ w1,
    const float* __restrict__ w2, const float* __restrict__ w3,
    _Float16* __restrict__ wt, _Float16* __restrict__ xw) {
  const int cb = blockIdx.x;
  if (cb < 4096) {
    const int z = cb >> 10, rem = cb & 1023;
    const float* w = (z == 0) ? w0 : (z == 1) ? w1 : (z == 2) ? w2 : w3;
    _Float16* outp = wt + (size_t)z * HID * HID;
    __shared__ float tile[32][33];
    const int tx = threadIdx.x & 31, ty = threadIdx.x >> 5;
    const int k0 = (rem >> 5) * 32, n0 = (rem & 31) * 32;
#pragma unroll
    for (int q = 0; q < 4; ++q) {
      int r = ty + q * 8;
      tile[r][tx] = w[(size_t)(k0 + r) * HID + n0 + tx];
    }
    __syncthreads();
#pragma unroll
    for (int q = 0; q < 4; ++q) {
      int r = ty + q * 8;
      outp[(size_t)(n0 + r) * HID + k0 + tx] = (_Float16)tile[tx][r];
    }
  } else {
    int i = (cb - 4096) * 256 + threadIdx.x;  // f4 index in [0, B*256)
    int b = i >> 8;
    int r = i & 255;
    int f = r >> 4;
    int e4 = r & 15;
    int id = idx[b * F_N + f];
    float4 v = *(const float4*)(emb + ((size_t)f * V_SZ + id) * E_SZ + e4 * 4);
    f16x4 h = {(_Float16)v.x, (_Float16)v.y, (_Float16)v.z, (_Float16)v.w};
    *(f16x4*)(xw + (size_t)b * HID + r * 4) = h;
  }
}

// ---------------------------------------------------------------------------
// C = relu(A @ Wt^T + bias) -> f16.  MFMA 16x16x32_f16.
// 128x128 tile, BK=64, 8 waves (512 thr) split 2M x 4N (64x32 per wave),
// 2 LDS buffers (64KB), depth-1 prefetch with counted vmcnt, 2 barriers/iter.
// LDS bank fix: pre-swizzled global source chunk (c ^ s3(row)), linear LDS
// dest (global_load_lds requirement), swizzled read.
// XCD-aware block swizzle: each XCD owns 4 row-panels x all 8 col-slices.
// ---------------------------------------------------------------------------
__global__ __launch_bounds__(512) void gemm_mfma(
    const _Float16* __restrict__ A, const _Float16* __restrict__ Wt,
    const float* __restrict__ bias, _Float16* __restrict__ C) {
  __shared__ _Float16 As[2][128 * 64];  // 32 KB
  __shared__ _Float16 Bs[2][128 * 64];  // 32 KB

  const int t = threadIdx.x;
  // XCD swizzle: XCD k (= bid%8) gets linear ids [k*32, k*32+32) = row-panels
  // 4k..4k+3 x all 8 col-panels -> A panel read once per XCD, Wt L2-resident.
  const int l = ((blockIdx.x & 7) << 5) | (blockIdx.x >> 3);
  const int bm = (l >> 3) * 128, bn = (l & 7) * 128;

  const int w = t >> 6, lane = t & 63;
  const int wr = w >> 2, wc = w & 3;       // 2M x 4N
  const int lr = lane & 15, lg = lane >> 4;

  // --- staging map: slot s in [0,1024): row=s>>3, chunk=s&7 (16B units).
  // thread t owns slots {t, t+512} of each matrix; same csrc for both.
  const int srow = t >> 3;
  const int cdst = t & 7;
  const int csrc = cdst ^ s3(srow);
  const _Float16* ga0 = A + (size_t)(bm + srow) * HID + csrc * 8;
  const _Float16* gb0 = Wt + (size_t)(bn + srow) * HID + csrc * 8;
  const int ld0 = t * 8, ld1 = t * 8 + 4096;  // halves, linear dest

  // --- frag read offsets (halves), kk=0; kk=1 = offset ^ 32.
  int aoff[4], boff[2];
#pragma unroll
  for (int mi = 0; mi < 4; mi++) {
    int ra = wr * 64 + mi * 16 + lr;
    aoff[mi] = ra * 64 + ((lg ^ s3(ra)) * 8);
  }
#pragma unroll
  for (int ni = 0; ni < 2; ni++) {
    int rb = wc * 32 + ni * 16 + lr;
    boff[ni] = rb * 64 + ((lg ^ s3(rb)) * 8);
  }

  f32x4 acc[4][2] = {};

#define STAGE(buf, ko)                              \
  gload16(ga0 + (ko), &As[buf][ld0]);               \
  gload16(ga0 + (ko) + 64 * HID, &As[buf][ld1]);    \
  gload16(gb0 + (ko), &Bs[buf][ld0]);               \
  gload16(gb0 + (ko) + 64 * HID, &Bs[buf][ld1]);

  STAGE(0, 0)  // tile 0

  for (int tI = 0; tI < 16; ++tI) {
    const int cur = tI & 1;
    if (tI < 15) {
      STAGE(cur ^ 1, (tI + 1) * 64)  // prefetch next tile (4 loads/thread)
    }
    if (tI < 15)
      asm volatile("s_waitcnt vmcnt(4)" ::: "memory");  // tile tI landed
    else
      asm volatile("s_waitcnt vmcnt(0)" ::: "memory");
    asm volatile("s_barrier" ::: "memory");

    f16x8 a0[4], a1[4], b0[2], b1[2];
#pragma unroll
    for (int mi = 0; mi < 4; mi++) {
      a0[mi] = *(const f16x8*)&As[cur][aoff[mi]];
      a1[mi] = *(const f16x8*)&As[cur][aoff[mi] ^ 32];
    }
#pragma unroll
    for (int ni = 0; ni < 2; ni++) {
      b0[ni] = *(const f16x8*)&Bs[cur][boff[ni]];
      b1[ni] = *(const f16x8*)&Bs[cur][boff[ni] ^ 32];
    }
#pragma unroll
    for (int mi = 0; mi < 4; mi++)
#pragma unroll
      for (int ni = 0; ni < 2; ni++) {
        acc[mi][ni] = __builtin_amdgcn_mfma_f32_16x16x32_f16(
            a0[mi], b0[ni], acc[mi][ni], 0, 0, 0);
        acc[mi][ni] = __builtin_amdgcn_mfma_f32_16x16x32_f16(
            a1[mi], b1[ni], acc[mi][ni], 0, 0, 0);
      }

    // all waves done reading buf cur before next iter's STAGE overwrites it
    asm volatile("s_barrier" ::: "memory");
  }
#undef STAGE

  // epilogue: D col = lane&15, row = lg*4 + j within each 16x16 frag
#pragma unroll
  for (int ni = 0; ni < 2; ni++) {
    int col = bn + wc * 32 + ni * 16 + lr;
    float bv = bias[col];
#pragma unroll
    for (int mi = 0; mi < 4; mi++) {
      int rbase = bm + wr * 64 + mi * 16 + lg * 4;
#pragma unroll
      for (int j = 0; j < 4; j++) {
        float x = acc[mi][ni][j] + bv;
        x = x > 0.f ? x : 0.f;
        C[(size_t)(rbase + j) * HID + col] = (_Float16)x;
      }
    }
  }
}

// ---------------------------------------------------------------------------
// Attention-over-layers + final dot; reads f16 activations, fp32 math.
// Hm[b,j] = cat[3b+j] with cat = [l0; l1; l2] row-stacked.
// ---------------------------------------------------------------------------
__global__ __launch_bounds__(256) void attn_final(
    const _Float16* __restrict__ cat, const _Float16* __restrict__ lf,
    const float* __restrict__ wf, const float* __restrict__ bfin,
    float* __restrict__ out) {
  const int wave = threadIdx.x >> 6;
  const int lane = threadIdx.x & 63;
  const int b = blockIdx.x * 4 + wave;

  const _Float16* h0 = cat + (size_t)(3 * b + 0) * 1024;
  const _Float16* h1 = cat + (size_t)(3 * b + 1) * 1024;
  const _Float16* h2 = cat + (size_t)(3 * b + 2) * 1024;
  const _Float16* lfr = lf + (size_t)b * 1024;

  float s01 = 0.f, s02 = 0.f, s12 = 0.f;
  float d0 = 0.f, d1 = 0.f, d2 = 0.f, dl = 0.f;

#pragma unroll
  for (int q = 0; q < 2; ++q) {
    int e8 = (lane + q * 64) * 8;
    f16x8 a0 = *(const f16x8*)(h0 + e8);
    f16x8 a1 = *(const f16x8*)(h1 + e8);
    f16x8 a2 = *(const f16x8*)(h2 + e8);
    f16x8 al = *(const f16x8*)(lfr + e8);
    float4 u0a = *(const float4*)(wf + e8);
    float4 u0b = *(const float4*)(wf + e8 + 4);
    float4 u1a = *(const float4*)(wf + 1024 + e8);
    float4 u1b = *(const float4*)(wf + 1024 + e8 + 4);
    float wf0[8] = {u0a.x, u0a.y, u0a.z, u0a.w, u0b.x, u0b.y, u0b.z, u0b.w};
    float wf1[8] = {u1a.x, u1a.y, u1a.z, u1a.w, u1b.x, u1b.y, u1b.z, u1b.w};
#pragma unroll
    for (int j = 0; j < 8; ++j) {
      float p0 = (float)a0[j], p1 = (float)a1[j], p2 = (float)a2[j];
      float pl = (float)al[j];
      s01 = fmaf(p0, p1, s01);
      s02 = fmaf(p0, p2, s02);
      s12 = fmaf(p1, p2, s12);
      d0 = fmaf(p0, wf1[j], d0);
      d1 = fmaf(p1, wf1[j], d1);
      d2 = fmaf(p2, wf1[j], d2);
      dl = fmaf(pl, wf0[j], dl);
    }
  }

#pragma unroll
  for (int m = 1; m < 64; m <<= 1) {
    s01 += __shfl_xor(s01, m);
    s02 += __shfl_xor(s02, m);
    s12 += __shfl_xor(s12, m);
    d0 += __shfl_xor(d0, m);
    d1 += __shfl_xor(d1, m);
    d2 += __shfl_xor(d2, m);
    dl += __shfl_xor(dl, m);
  }

  if (lane == 0) {
    float c0 = 0.f, c1 = 0.f, c2 = 0.f;
    {
      float m = fmaxf(0.f, fmaxf(s01, s02));
      float e0 = expf(0.f - m), e1 = expf(s01 - m), e2 = expf(s02 - m);
      float inv = 1.f / (e0 + e1 + e2);
      c0 += e0 * inv; c1 += e1 * inv; c2 += e2 * inv;
    }
    {
      float m = fmaxf(s01, fmaxf(0.f, s12));
      float e0 = expf(s01 - m), e1 = expf(0.f - m), e2 = expf(s12 - m);
      float inv = 1.f / (e0 + e1 + e2);
      c0 += e0 * inv; c1 += e1 * inv; c2 += e2 * inv;
    }
    {
      float m = fmaxf(s02, fmaxf(s12, 0.f));
      float e0 = expf(s02 - m), e1 = expf(s12 - m), e2 = expf(0.f - m);
      float inv = 1.f / (e0 + e1 + e2);
      c0 += e0 * inv; c1 += e1 * inv; c2 += e2 * inv;
    }
    out[b] = dl + c0 * d0 + c1 * d1 + c2 * d2 + bfin[0];
  }
}

// ---------------------------------------------------------------------------
extern "C" void kernel_launch(void* const* d_in, const int* in_sizes, int n_in,
                              void* d_out, int out_size, void* d_ws,
                              size_t ws_size, hipStream_t stream) {
  const int* idx = (const int*)d_in[0];
  const float* emb = (const float*)d_in[1];
  const float* w0 = (const float*)d_in[2];
  const float* b0 = (const float*)d_in[3];
  const float* w1 = (const float*)d_in[4];
  const float* b1 = (const float*)d_in[5];
  const float* w2 = (const float*)d_in[6];
  const float* b2 = (const float*)d_in[7];
  const float* w3 = (const float*)d_in[8];
  const float* b3 = (const float*)d_in[9];
  const float* wf = (const float*)d_in[10];
  const float* bfin = (const float*)d_in[11];
  float* out = (float*)d_out;

  const size_t RB = (size_t)B_SZ * HID;   // 4M elements
  const size_t WSZ = (size_t)HID * HID;   // 1M elements

  _Float16* wt = (_Float16*)d_ws;        // [4][1024][1024]  8 MB
  _Float16* xw16 = wt + 4 * WSZ;         // [B,1024]         8 MB
  _Float16* cat16 = xw16 + RB;           // [3B,1024]       24 MB
  _Float16* lf16 = cat16 + 3 * RB;       // [B,1024]         8 MB

  prep<<<8192, 256, 0, stream>>>(idx, emb, w0, w1, w2, w3, wt, xw16);

  gemm_mfma<<<256, 512, 0, stream>>>(xw16, wt + 0 * WSZ, b0, cat16);
  gemm_mfma<<<256, 512, 0, stream>>>(cat16, wt + 1 * WSZ, b1, cat16 + RB);
  gemm_mfma<<<256, 512, 0, stream>>>(cat16 + RB, wt + 2 * WSZ, b2,
                                     cat16 + 2 * RB);
  gemm_mfma<<<256, 512, 0, stream>>>(cat16 + 2 * RB, wt + 3 * WSZ, b3, lf16);

  attn_final<<<B_SZ / 4, 256, 0, stream>>>(cat16, lf16, wf, bfin, out);
}